// Round 7
// baseline (33.026 us; speedup 1.0000x reference)
//
#include <hip/hip_runtime.h>
#include <math.h>

#define BB 32
#define LL 512
#define DD 1024
#define TT 256
#define NK 136393              // kept (s,e) pairs per batch
#define NK_LIN 131273          // off(502)
#define S_LIN 502
#define NEG_BIG  -3.0e38f      // finite stand-in for -inf
#define NEG_MASK -1.0e30f      // finite stand-in for masked logits
#define P_TOT (BB * NK)        // 4364576 pairs (multiple of 4)
#define FILL_THREADS (P_TOT / 4)
#define FILL_BLOCKS ((FILL_THREADS + 255) / 256)   // 4263

typedef float f4v __attribute__((ext_vector_type(4)));

// ---- d1: pure GEMV read-stream. logits = text @ W + b, wave per row. ------
__global__ __launch_bounds__(256) void gemv_kernel(
    const float* __restrict__ text, const float* __restrict__ W,
    const float* __restrict__ bias, const int* __restrict__ mask,
    float* __restrict__ slp, float* __restrict__ elp, float* __restrict__ mlp)
{
    const int wid  = threadIdx.x >> 6;
    const int lane = threadIdx.x & 63;
    const int row  = blockIdx.x * 4 + wid;        // row = b*L + l
    const f4v* t4 = (const f4v*)(text + (size_t)row * DD);
    const f4v* w4 = (const f4v*)W;

    float a0 = 0.f, a1 = 0.f, a2 = 0.f;
#pragma unroll
    for (int j = 0; j < 4; ++j) {
        const int fi = lane + j * 64;
        f4v v  = t4[fi];                          // coalesced 1KB/instr/wave
        f4v w0 = w4[fi * 3 + 0];                  // L1-hot
        f4v w1 = w4[fi * 3 + 1];
        f4v w2 = w4[fi * 3 + 2];
        a0 += v.x * w0.x;  a1 += v.x * w0.y;  a2 += v.x * w0.z;
        a0 += v.y * w0.w;  a1 += v.y * w1.x;  a2 += v.y * w1.y;
        a0 += v.z * w1.z;  a1 += v.z * w1.w;  a2 += v.z * w2.x;
        a0 += v.w * w2.y;  a1 += v.w * w2.z;  a2 += v.w * w2.w;
    }
#pragma unroll
    for (int o = 32; o; o >>= 1) {
        a0 += __shfl_down(a0, o);
        a1 += __shfl_down(a1, o);
        a2 += __shfl_down(a2, o);
    }
    if (lane == 0) {
        const int m = mask[row];
        slp[row] = (m == 1) ? a0 + bias[0] : NEG_MASK;
        elp[row] = (m == 1) ? a1 + bias[1] : NEG_MASK;
        mlp[row] = (m == 1) ? a2 + bias[2] : NEG_MASK;
    }
}

// ---- d2: pure emit write-stream. Every position written once, final. -----
// Thread handles 4 consecutive pairs: score float4 + 2 bounds float4s (48B).
// Flags for the block's (<=2) batches live in LDS; valid pairs (~1.6%)
// gather slp/elp/mlp from the 192KB L2-resident intermediate.
__global__ __launch_bounds__(256) void emit_kernel(
    const float* __restrict__ slp, const float* __restrict__ elp,
    const float* __restrict__ mlp, const int* __restrict__ mask,
    const int* __restrict__ tmap, float* __restrict__ out)
{
    __shared__ unsigned char ts0[LL], te0[LL], ts1[LL], te1[LL];
    const int t = threadIdx.x;
    const int i = blockIdx.x * 256 + t;
    const int idx0 = blockIdx.x * 1024;           // block's first pair
    const int b0 = idx0 / NK;
    const int bX = min(b0 + 1, BB - 1);           // possible spill-over batch

    ts0[t] = 0; ts0[t + 256] = 0; te0[t] = 0; te0[t + 256] = 0;
    ts1[t] = 0; ts1[t + 256] = 0; te1[t] = 0; te1[t + 256] = 0;
    __syncthreads();
    {   // t in [0,256) == TT: one tmap entry per thread per batch
        int s0 = tmap[((size_t)b0 * TT + t) * 2 + 0];
        int e0 = tmap[((size_t)b0 * TT + t) * 2 + 1] - 1;
        s0 = min(max(s0, 0), LL - 1); e0 = min(max(e0, 0), LL - 1);
        ts0[s0] = 1; te0[e0] = 1;                 // benign race: all write 1
        int s1 = tmap[((size_t)bX * TT + t) * 2 + 0];
        int e1 = tmap[((size_t)bX * TT + t) * 2 + 1] - 1;
        s1 = min(max(s1, 0), LL - 1); e1 = min(max(e1, 0), LL - 1);
        ts1[s1] = 1; te1[e1] = 1;
    }
    __syncthreads();

    if (i >= FILL_THREADS) return;                // after all barriers: safe
    const int idx = i * 4;

    int b = idx / NK;                             // magic-mul division
    int k = idx - b * NK;
    int s, e;
    if (k >= NK_LIN) {
        const int r = k - NK_LIN;
        s = S_LIN + (r >> 9);
        e = r & 511;
    } else {
        float f = sqrtf(8.0f * (float)k + 441.0f);
        s = (int)((f - 21.0f) * 0.5f);
        if (s < 0) s = 0;
        if (s > 501) s = 501;
        while ((s + 1) * (s + 22) / 2 <= k) ++s;
        while (s * (s + 21) / 2 > k) --s;
        e = k - s * (s + 21) / 2;
    }

    float sc[4], bnd[8];
#pragma unroll
    for (int j = 0; j < 4; ++j) {
        float v = NEG_BIG;
        const unsigned char* ts = (b == b0) ? ts0 : ts1;
        const unsigned char* te = (b == b0) ? te0 : te1;
        if (s > 0 && e >= s && ts[s] && te[e] && mask[b * LL + s] == 1) {
            const int base = b * LL;
            float w = 0.f;
            for (int l = s; l <= e; ++l) w += mlp[base + l];  // <=11, L2-hot
            v = slp[base + s] + elp[base + e] + w;
            if (v < -1.0e29f) v = NEG_BIG;        // masked row -> -inf in ref
        }
        sc[j] = v;
        bnd[2 * j] = (float)s; bnd[2 * j + 1] = (float)e;
        ++e;                                      // advance to next pair
        const int rowlen = (s <= S_LIN) ? (s + 11) : LL;
        if (e >= rowlen) { e = 0; if (++s >= LL) { s = 0; ++b; } }
    }

    f4v sv = {sc[0], sc[1], sc[2], sc[3]};
    *(f4v*)(out + idx) = sv;                      // 16B-aligned (idx%4==0)
    f4v* bp = (f4v*)(out + (size_t)P_TOT + (size_t)2 * idx);  // P_TOT%4==0
    f4v bv0 = {bnd[0], bnd[1], bnd[2], bnd[3]};
    f4v bv1 = {bnd[4], bnd[5], bnd[6], bnd[7]};
    bp[0] = bv0; bp[1] = bv1;
}

extern "C" void kernel_launch(void* const* d_in, const int* in_sizes, int n_in,
                              void* d_out, int out_size, void* d_ws, size_t ws_size,
                              hipStream_t stream) {
    const float* text = (const float*)d_in[0];   // (B,L,D) f32
    const int*   mask = (const int*)d_in[1];     // (B,L) i32
    const int*   tmap = (const int*)d_in[2];     // (B,T,2) i32
    const float* W    = (const float*)d_in[3];   // (D,3) f32
    const float* bias = (const float*)d_in[4];   // (3,) f32
    float* out = (float*)d_out;

    float* slp = (float*)d_ws;                   // B*L each
    float* elp = slp + (size_t)BB * LL;
    float* mlp = elp + (size_t)BB * LL;

    gemv_kernel<<<BB * LL / 4, 256, 0, stream>>>(text, W, bias, mask,
                                                 slp, elp, mlp);
    emit_kernel<<<FILL_BLOCKS, 256, 0, stream>>>(slp, elp, mlp, mask, tmap, out);
}